// Round 5
// baseline (666.949 us; speedup 1.0000x reference)
//
#include <hip/hip_runtime.h>
#include <hip/hip_bf16.h>
#include <math.h>

#define B_SZ 32
#define VLEN_SZ 2048
#define H_SZ 1024
#define DIM_SZ 1024
#define C_SZ 32

typedef float f32x4 __attribute__((ext_vector_type(4)));
typedef short s16x8 __attribute__((ext_vector_type(8)));
typedef short s16x4 __attribute__((ext_vector_type(4)));

__device__ __forceinline__ short f2bf(float f) {
  unsigned u = __float_as_uint(f);
  u = (u + 0x7fffu + ((u >> 16) & 1u)) >> 16;  // RNE
  return (short)u;
}

__device__ __forceinline__ float bf2f(short s) {
  return __uint_as_float(((unsigned)(unsigned short)s) << 16);
}

__device__ __forceinline__ float fast_tanh(float x) {
  float z = __expf(2.0f * x);
  return 1.0f - 2.0f / (z + 1.0f);
}

// async 16B global -> LDS (wave-uniform LDS base + lane*16)
__device__ __forceinline__ void ldg_lds16(const void* g, void* l) {
  __builtin_amdgcn_global_load_lds(
      (const __attribute__((address_space(1))) unsigned int*)g,
      (__attribute__((address_space(3))) unsigned int*)l, 16, 0, 0);
}

// ---- fused prep: qpb + conv-features + weight casts + value cast + zeroing ----
// role by block range:
//   [0,8192)      qp[b,d] = dot(query[b],w_q[d]) + bias[d]   (one wave per (b,d))
//   [8192,8448)   conv features cf[b,v,c] bf16 (vectorized stores)
//   [8448,8480)   w_loc -> bf16
//   [8480,9504)   w_v   -> bf16
//   [9504,9568)   zero score
//   [9568,9600)   zero context
//   [9600,42368)  value -> bf16 (8 elems/thread)
__global__ __launch_bounds__(256) void k_prep(
    const float* __restrict__ query, const float* __restrict__ w_q,
    const float* __restrict__ bias, const float* __restrict__ prev,
    const float* __restrict__ conv_w, const float* __restrict__ conv_b,
    const float* __restrict__ w_loc, const float* __restrict__ w_v,
    const float* __restrict__ value,
    float* __restrict__ qpb, short* __restrict__ cfb, short* __restrict__ wlocb,
    short* __restrict__ wvb, short* __restrict__ vb,
    float* __restrict__ score, float* __restrict__ context) {
  int bid = blockIdx.x;
  int t = threadIdx.x;
  if (bid < 8192) {
    int wid = bid * 4 + (t >> 6);
    int lane = t & 63;
    int d = wid >> 5;
    int b = wid & 31;
    const f32x4* q4 = (const f32x4*)(query + (size_t)b * H_SZ);
    const f32x4* w4 = (const f32x4*)(w_q + (size_t)d * H_SZ);
    float acc = 0.f;
#pragma unroll
    for (int it = 0; it < 4; ++it) {
      int k = it * 64 + lane;
      f32x4 a = q4[k], w = w4[k];
      acc += a[0] * w[0] + a[1] * w[1] + a[2] * w[2] + a[3] * w[3];
    }
#pragma unroll
    for (int off = 32; off; off >>= 1) acc += __shfl_xor(acc, off, 64);
    if (lane == 0) qpb[(size_t)b * DIM_SZ + d] = acc + bias[d];
  } else if (bid < 8448) {
    int r = (bid - 8192) * 256 + t;  // row index b*VLEN+v
    int v = r & (VLEN_SZ - 1);
    float p0 = prev[r];
    float pm = (v > 0) ? prev[r - 1] : 0.f;
    float pp = (v < VLEN_SZ - 1) ? prev[r + 1] : 0.f;
    float o[C_SZ];
#pragma unroll
    for (int c = 0; c < C_SZ; ++c)
      o[c] = conv_b[c] + pm * conv_w[c * 3 + 0] + p0 * conv_w[c * 3 + 1] + pp * conv_w[c * 3 + 2];
    s16x8* dst = (s16x8*)(cfb + (size_t)r * C_SZ);
#pragma unroll
    for (int g = 0; g < 4; ++g) {
      s16x8 pk;
#pragma unroll
      for (int e = 0; e < 8; ++e) pk[e] = f2bf(o[8 * g + e]);
      dst[g] = pk;
    }
  } else if (bid < 8480) {
    int i = (bid - 8448) * 256 + t;  // n4 = 8192
    f32x4 v = ((const f32x4*)w_loc)[i];
    s16x4 o;
    o[0] = f2bf(v[0]); o[1] = f2bf(v[1]); o[2] = f2bf(v[2]); o[3] = f2bf(v[3]);
    ((s16x4*)wlocb)[i] = o;
  } else if (bid < 9504) {
    int i = (bid - 8480) * 256 + t;  // n4 = 262144
    f32x4 v = ((const f32x4*)w_v)[i];
    s16x4 o;
    o[0] = f2bf(v[0]); o[1] = f2bf(v[1]); o[2] = f2bf(v[2]); o[3] = f2bf(v[3]);
    ((s16x4*)wvb)[i] = o;
  } else if (bid < 9568) {
    int i = (bid - 9504) * 256 + t;  // 16384 f32x4
    ((f32x4*)score)[i] = (f32x4){0.f, 0.f, 0.f, 0.f};
  } else if (bid < 9600) {
    int i = (bid - 9568) * 256 + t;  // 8192 f32x4
    ((f32x4*)context)[i] = (f32x4){0.f, 0.f, 0.f, 0.f};
  } else {
    size_t i = (size_t)(bid - 9600) * 256 + t;  // s16x8 group
    f32x4 x0 = ((const f32x4*)value)[2 * i];
    f32x4 x1 = ((const f32x4*)value)[2 * i + 1];
    s16x8 o;
    o[0] = f2bf(x0[0]); o[1] = f2bf(x0[1]); o[2] = f2bf(x0[2]); o[3] = f2bf(x0[3]);
    o[4] = f2bf(x1[0]); o[5] = f2bf(x1[1]); o[6] = f2bf(x1[2]); o[7] = f2bf(x1[3]);
    ((s16x8*)vb)[i] = o;
  }
}

// ---- main fused kernel: 128x128 tile GEMM + lp K-step + tanh + score ----
// r3-proven structure (bf16 A via vb, 0 bank conflicts). XCD-aware 1-D grid
// 4096: x = bid%8 is the XCD under round-robin dispatch; XCD x owns mt in
// [x*64, x*64+64), its 8 nt blocks per mt consecutive -> A-tile served by one
// XCD's L2.
__global__ __launch_bounds__(256, 4) void k_score(
    const short* __restrict__ vb, const short* __restrict__ wvb,
    const short* __restrict__ wlocb, const short* __restrict__ cfb,
    const float* __restrict__ qpb, const float* __restrict__ w_score,
    float* __restrict__ score) {
  __shared__ short As[128 * 32];   // 8 KB, [m][32k] with XOR-swizzled 8-elem chunks
  __shared__ short Bs[128 * 32];   // 8 KB
  __shared__ float sred[4][64];

  int t = threadIdx.x;
  int w = t >> 6, l = t & 63;
  int q = l >> 4, l16 = l & 15;
  int bid = blockIdx.x;
  int x = bid & 7;
  int j = bid >> 3;
  int nt = j & 7;                  // 0..7
  int mt = x * 64 + (j >> 3);      // 0..511
  int row0 = mt * 128;             // global row base (b*VLEN+v)
  int d0 = nt * 128;
  int b = row0 >> 11;              // VLEN = 2048
  int wm = w >> 1, wn = w & 1;

  // staging: one instr = 16 rows x 32 k (1 KB). lane l -> row lr = l>>2,
  // position chunk l&3; CONTENT chunk = (l&3) ^ ((l>>3)&3) so chunk c of
  // row m lives at position c ^ ((m>>1)&3)  (conflict-free fragment reads)
  int lr = l >> 2;
  int kc = ((l & 3) ^ ((l >> 3) & 3)) * 8;

  const short* gA0 = vb + (size_t)(row0 + 32 * w + lr) * H_SZ + kc;
  const short* gA1 = vb + (size_t)(row0 + 32 * w + 16 + lr) * H_SZ + kc;
  const short* gB0 = wvb + (size_t)(d0 + 32 * w + lr) * H_SZ + kc;
  const short* gB1 = wvb + (size_t)(d0 + 32 * w + 16 + lr) * H_SZ + kc;
  short* lA0 = As + (32 * w) * 32;
  short* lA1 = As + (32 * w + 16) * 32;
  short* lB0 = Bs + (32 * w) * 32;
  short* lB1 = Bs + (32 * w + 16) * 32;

  int posA = (q ^ ((l16 >> 1) & 3)) * 8;

  f32x4 acc[4][4];
#pragma unroll
  for (int i = 0; i < 4; ++i)
#pragma unroll
    for (int jj = 0; jj < 4; ++jj) acc[i][jj] = (f32x4){0.f, 0.f, 0.f, 0.f};

  for (int kt = 0; kt <= 32; ++kt) {
    if (kt < 32) {
      int k0 = kt * 32;
      ldg_lds16(gA0 + k0, lA0);
      ldg_lds16(gA1 + k0, lA1);
      ldg_lds16(gB0 + k0, lB0);
      ldg_lds16(gB1 + k0, lB1);
    } else {
      // location-feature K-step: A = cf (row stride 32), B = w_loc
      ldg_lds16(cfb + (size_t)(row0 + 32 * w + lr) * C_SZ + kc, lA0);
      ldg_lds16(cfb + (size_t)(row0 + 32 * w + 16 + lr) * C_SZ + kc, lA1);
      ldg_lds16(wlocb + (size_t)(d0 + 32 * w + lr) * C_SZ + kc, lB0);
      ldg_lds16(wlocb + (size_t)(d0 + 32 * w + 16 + lr) * C_SZ + kc, lB1);
    }
    __syncthreads();

    s16x8 a[4], bb[4];
#pragma unroll
    for (int i = 0; i < 4; ++i)
      a[i] = *(const s16x8*)(As + (wm * 64 + i * 16 + l16) * 32 + posA);
#pragma unroll
    for (int jj = 0; jj < 4; ++jj)
      bb[jj] = *(const s16x8*)(Bs + (wn * 64 + jj * 16 + l16) * 32 + posA);
#pragma unroll
    for (int i = 0; i < 4; ++i)
#pragma unroll
      for (int jj = 0; jj < 4; ++jj)
        acc[i][jj] = __builtin_amdgcn_mfma_f32_16x16x32_bf16(a[i], bb[jj], acc[i][jj], 0, 0, 0);
    __syncthreads();
  }

  // epilogue: e = tanh(acc + qp[d]) (qp includes bias), score += e.w_score
  float qv[4], wv[4];
#pragma unroll
  for (int jj = 0; jj < 4; ++jj) {
    int d = d0 + wn * 64 + jj * 16 + l16;
    qv[jj] = qpb[(size_t)b * DIM_SZ + d];
    wv[jj] = w_score[d];
  }

#pragma unroll
  for (int i = 0; i < 4; ++i) {
#pragma unroll
    for (int r = 0; r < 4; ++r) {
      float part = 0.f;
#pragma unroll
      for (int jj = 0; jj < 4; ++jj)
        part += fast_tanh(acc[i][jj][r] + qv[jj]) * wv[jj];
      part += __shfl_xor(part, 1);
      part += __shfl_xor(part, 2);
      part += __shfl_xor(part, 4);
      part += __shfl_xor(part, 8);
      if (l16 == 0) sred[w][i * 16 + q * 4 + r] = part;
    }
  }
  __syncthreads();
  if (t < 128) {
    int half = t >> 6;
    float v = sred[half * 2][t & 63] + sred[half * 2 + 1][t & 63];
    atomicAdd(&score[row0 + t], v);
  }
}

// ---- fused sigmoid-normalize + context partial; grid (32 b, 16 vc) ----
// per block: recompute full attn row for b (cheap, L2-resident score), then
// 128-v x 1024-h partial context with bf16 s16x8 loads; 8 atomics/thread.
__global__ __launch_bounds__(256) void k_ctx(
    const float* __restrict__ score, const float* __restrict__ b_score,
    const short* __restrict__ vb, float* __restrict__ attn_out,
    float* __restrict__ context) {
  __shared__ float als[VLEN_SZ];
  __shared__ float red[4];
  int b = blockIdx.x, vc = blockIdx.y, t = threadIdx.x;
  float bs = b_score[0];
  float sv[8];
  float lsum = 0.f;
  int v0 = t * 8;
#pragma unroll
  for (int k = 0; k < 8; ++k) {
    float ps = score[(size_t)b * VLEN_SZ + v0 + k] + bs;
    float s = 1.0f / (1.0f + __expf(-ps));
    sv[k] = s;
    lsum += s;
    als[v0 + k] = s;
  }
#pragma unroll
  for (int off = 32; off; off >>= 1) lsum += __shfl_xor(lsum, off, 64);
  if ((t & 63) == 0) red[t >> 6] = lsum;
  __syncthreads();
  float inv = 1.0f / (red[0] + red[1] + red[2] + red[3]);
  if (vc == 0) {
#pragma unroll
    for (int k = 0; k < 8; ++k)
      attn_out[(size_t)b * VLEN_SZ + v0 + k] = sv[k] * inv;
  }

  int p = t >> 7, tt = t & 127;
  int h0 = tt * 8;
  int vbase = vc * 128 + p * 64;
  const short* vp = vb + ((size_t)b * VLEN_SZ + vbase) * H_SZ + h0;
  const float* av = als + vbase;
  float acc[8] = {0.f, 0.f, 0.f, 0.f, 0.f, 0.f, 0.f, 0.f};
#pragma unroll 4
  for (int v = 0; v < 64; ++v) {
    s16x8 xv = *(const s16x8*)(vp + (size_t)v * H_SZ);
    float a = av[v];
#pragma unroll
    for (int k = 0; k < 8; ++k) acc[k] += a * bf2f(xv[k]);
  }
#pragma unroll
  for (int k = 0; k < 8; ++k)
    atomicAdd(&context[(size_t)b * H_SZ + h0 + k], acc[k] * inv);
}

// ---- out[b,h] = b_out[h] + [context|query] . w_out[h,:]; one wave per output ----
__global__ void k_out(const float* __restrict__ context, const float* __restrict__ query,
                      const float* __restrict__ w_out, const float* __restrict__ b_out,
                      float* __restrict__ out) {
  int wid = blockIdx.x * 4 + (threadIdx.x >> 6);
  int lane = threadIdx.x & 63;
  int h = wid >> 5;
  int b = wid & 31;
  const f32x4* w4 = (const f32x4*)(w_out + (size_t)h * 2048);
  const f32x4* c4 = (const f32x4*)(context + (size_t)b * H_SZ);
  const f32x4* q4 = (const f32x4*)(query + (size_t)b * H_SZ);
  float acc = 0.f;
#pragma unroll
  for (int it = 0; it < 8; ++it) {
    int k4 = it * 64 + lane;
    f32x4 w = w4[k4];
    f32x4 c = (k4 < 256) ? c4[k4] : q4[k4 - 256];
    acc += w[0] * c[0] + w[1] * c[1] + w[2] * c[2] + w[3] * c[3];
  }
#pragma unroll
  for (int off = 32; off; off >>= 1) acc += __shfl_xor(acc, off, 64);
  if (lane == 0) out[(size_t)b * H_SZ + h] = acc + b_out[h];
}

extern "C" void kernel_launch(void* const* d_in, const int* in_sizes, int n_in,
                              void* d_out, int out_size, void* d_ws, size_t ws_size,
                              hipStream_t stream) {
  const float* query   = (const float*)d_in[0];
  const float* value   = (const float*)d_in[1];
  const float* prev    = (const float*)d_in[2];
  const float* conv_w  = (const float*)d_in[3];
  const float* conv_b  = (const float*)d_in[4];
  const float* w_loc   = (const float*)d_in[5];
  const float* w_q     = (const float*)d_in[6];
  const float* w_v     = (const float*)d_in[7];
  const float* bias    = (const float*)d_in[8];
  const float* w_score = (const float*)d_in[9];
  const float* b_score = (const float*)d_in[10];
  const float* w_out   = (const float*)d_in[11];
  const float* b_out   = (const float*)d_in[12];

  float* out  = (float*)d_out;                 // (B,1,H) = 32768 floats
  float* attn = out + B_SZ * H_SZ;             // (B,V)   = 65536 floats

  char* ws = (char*)d_ws;
  float* score   = (float*)(ws);               // 256 KB
  float* qpb     = (float*)(ws + (256 << 10)); // 128 KB
  float* context = (float*)(ws + (384 << 10)); // 128 KB
  short* wvb     = (short*)(ws + (512 << 10)); // 2 MB   bf16 w_v
  short* wlocb   = (short*)(ws + (2560 << 10));// 64 KB  bf16 w_loc
  short* cfb     = (short*)(ws + (3 << 20));   // 4 MB   bf16 conv features
  short* vb      = (short*)(ws + (8 << 20));   // 128 MB bf16 value

  k_prep<<<42368, 256, 0, stream>>>(query, w_q, bias, prev, conv_w, conv_b,
                                    w_loc, w_v, value,
                                    qpb, cfb, wlocb, wvb, vb, score, context);
  k_score<<<4096, 256, 0, stream>>>(vb, wvb, wlocb, cfb, qpb, w_score, score);
  k_ctx<<<dim3(B_SZ, 16), 256, 0, stream>>>(score, b_score, vb, attn, context);
  k_out<<<(B_SZ * H_SZ) / 4, 256, 0, stream>>>(context, query, w_out, b_out, out);
}